// Round 1
// baseline (571.740 us; speedup 1.0000x reference)
//
#include <hip/hip_runtime.h>
#include <hip/hip_bf16.h>
#include <math.h>

// DynSMHA: B=4 T=2048 C=1024 H=128 E=16 MIN_E=2, non-causal.
// Pipeline: fp64 gating -> expert bucketing -> grouped bf16-MFMA GEMMs
// (QKV, scores, PV, out-proj) with fp32 accumulation.
#define NBATCH 4
#define NT     2048
#define NC     1024
#define NH     128
#define NE     16
#define NTOK   (NBATCH * NT)
#define LDA    72            // LDS leading dim (64 + 8 bf16 pad -> conflict-free)
#define MAXTILES 2064        // worst case sum ceil(cnt_e/64) = 16 + 131072/64

typedef __bf16 bf16x8 __attribute__((ext_vector_type(8)));
typedef __bf16 bf16x4 __attribute__((ext_vector_type(4)));
typedef float  f32x4  __attribute__((ext_vector_type(4)));

__device__ __forceinline__ __bf16 f2bf(float f) { return (__bf16)f; }

// ---------------- sim column norms (fp64) ----------------
__global__ void k_colnorm(const float* __restrict__ sim, double* __restrict__ snorm) {
  int e = blockIdx.x, t = threadIdx.x;
  double a = 0.0;
  for (int c = t; c < NC; c += 256) { double v = (double)sim[(size_t)c * NE + e]; a += v * v; }
#pragma unroll
  for (int off = 32; off; off >>= 1) a += __shfl_down(a, off);
  __shared__ double red[4];
  if ((t & 63) == 0) red[t >> 6] = a;
  __syncthreads();
  if (t == 0) snorm[e] = fmax(sqrt(red[0] + red[1] + red[2] + red[3]), 1e-12);
}

// ------- transpose last two dims, fp32 -> bf16: in[G][R][Cd] -> out[G][Cd][R] -------
__global__ void k_transpose(const float* __restrict__ in, __bf16* __restrict__ out, int R, int Cd) {
  __shared__ float tile[32][33];
  int g = blockIdx.z;
  int r0 = blockIdx.x * 32, c0 = blockIdx.y * 32;
  int tx = threadIdx.x & 31, ty0 = threadIdx.x >> 5;
  const float* src = in + (size_t)g * R * Cd;
  __bf16* dst = out + (size_t)g * R * Cd;
#pragma unroll
  for (int ty = ty0; ty < 32; ty += 8)
    tile[ty][tx] = src[(size_t)(r0 + ty) * Cd + (c0 + tx)];
  __syncthreads();
#pragma unroll
  for (int ty = ty0; ty < 32; ty += 8)
    dst[(size_t)(c0 + ty) * R + (r0 + tx)] = f2bf(tile[tx][ty]);
}

// ---------------- gating (fp64) ----------------
__global__ void k_gating(const float* __restrict__ x, const float* __restrict__ sim,
                         const float* __restrict__ gates, const double* __restrict__ snorm,
                         float* __restrict__ w_all, int* __restrict__ counts) {
  int n = blockIdx.x, t = threadIdx.x;
  const float* xr = x + (size_t)n * NC;
  double acc[NE];
  double ax = 0.0;
#pragma unroll
  for (int e = 0; e < NE; e++) acc[e] = 0.0;
  for (int c = t; c < NC; c += 256) {
    double xv = (double)xr[c];
    ax += xv * xv;
    const float* sr = sim + (size_t)c * NE;
#pragma unroll
    for (int e = 0; e < NE; e++) acc[e] += xv * (double)sr[e];
  }
#pragma unroll
  for (int off = 32; off; off >>= 1) {
    ax += __shfl_down(ax, off);
#pragma unroll
    for (int e = 0; e < NE; e++) acc[e] += __shfl_down(acc[e], off);
  }
  __shared__ double red[4][NE + 1];
  int lane = t & 63, wid = t >> 6;
  if (lane == 0) {
    red[wid][NE] = ax;
#pragma unroll
    for (int e = 0; e < NE; e++) red[wid][e] = acc[e];
  }
  __syncthreads();
  if (t == 0) {
    double xn = fmax(sqrt(red[0][NE] + red[1][NE] + red[2][NE] + red[3][NE]), 1e-12);
    double logits[NE];
    unsigned act = 0;
    int cnt = 0;
    for (int e = 0; e < NE; e++) {
      double d = red[0][e] + red[1][e] + red[2][e] + red[3][e];
      double sig = 1.0 / (1.0 + exp(-(double)gates[e]));
      logits[e] = d / (xn * snorm[e]) - sig;
      if (logits[e] > 0.0) { act |= 1u << e; cnt++; }
    }
    if (cnt == 0) {  // fallback: top-MIN_E(=2) logits, jax.top_k tie-break = lowest index
      int i1 = 0; double b1 = logits[0];
      for (int e = 1; e < NE; e++) if (logits[e] > b1) { b1 = logits[e]; i1 = e; }
      int i2 = -1; double b2 = -1e300;
      for (int e = 0; e < NE; e++) if (e != i1 && logits[e] > b2) { b2 = logits[e]; i2 = e; }
      act = (1u << i1) | (1u << i2);
    }
    // softmax of gated(=relu(logits)) over active set
    double m = -1e300;
    for (int e = 0; e < NE; e++) if ((act >> e) & 1) m = fmax(m, fmax(logits[e], 0.0));
    double s = 0.0, wv[NE];
    for (int e = 0; e < NE; e++) {
      if ((act >> e) & 1) { wv[e] = exp(fmax(logits[e], 0.0) - m); s += wv[e]; }
      else wv[e] = 0.0;
    }
    for (int e = 0; e < NE; e++) {
      w_all[(size_t)n * NE + e] = ((act >> e) & 1) ? (float)(wv[e] / s) : 0.0f;
      if ((act >> e) & 1) atomicAdd(&counts[e], 1);
    }
  }
}

// ---------------- scan counts -> offsets + tile descriptors ----------------
__global__ void k_scan(const int* __restrict__ counts, int* __restrict__ offsets,
                       int2* __restrict__ tile_desc, int* __restrict__ n_tiles) {
  if (threadIdx.x == 0 && blockIdx.x == 0) {
    int off = 0, nt = 0;
    for (int e = 0; e < NE; e++) {
      offsets[e] = off;
      int c = counts[e];
      int tiles = (c + 63) >> 6;
      for (int t = 0; t < tiles; t++) { tile_desc[nt].x = e; tile_desc[nt].y = off + t * 64; nt++; }
      off += c;
    }
    offsets[NE] = off;
    *n_tiles = nt;
  }
}

// ---------------- slot assignment ----------------
__global__ void k_assign(const float* __restrict__ w_all, const int* __restrict__ offsets,
                         int* __restrict__ cursors, int* __restrict__ slot_token,
                         float* __restrict__ slot_w) {
  int n = blockIdx.x * 256 + threadIdx.x;
  if (n >= NTOK) return;
  for (int e = 0; e < NE; e++) {
    float w = w_all[(size_t)n * NE + e];
    if (w > 0.0f) {
      int p = atomicAdd(&cursors[e], 1);
      int s = offsets[e] + p;
      slot_token[s] = n;
      slot_w[s] = w;
    }
  }
}

// ---------------- shared MFMA inner tile: 64x128, BK=64 ----------------
__device__ __forceinline__ void mfma_block(const __bf16* As, const __bf16* Bs,
                                           int lane, int wrow, f32x4 acc[8]) {
#pragma unroll
  for (int ks = 0; ks < 2; ks++) {
    int koff = ks * 32 + (lane >> 4) * 8;
    bf16x8 af = *(const bf16x8*)&As[(wrow + (lane & 15)) * LDA + koff];
#pragma unroll
    for (int nt = 0; nt < 8; nt++) {
      bf16x8 bv = *(const bf16x8*)&Bs[(nt * 16 + (lane & 15)) * LDA + koff];
      acc[nt] = __builtin_amdgcn_mfma_f32_16x16x32_bf16(af, bv, acc[nt], 0, 0, 0);
    }
  }
}

// ---------------- grouped GEMM: QKV projections ----------------
__global__ __launch_bounds__(256) void k_moe_qkv(
    const float* __restrict__ x,
    const __bf16* __restrict__ pq, const __bf16* __restrict__ pk, const __bf16* __restrict__ pv,
    const int* __restrict__ slot_token, const float* __restrict__ slot_w,
    const int* __restrict__ offsets, const int2* __restrict__ tile_desc,
    const int* __restrict__ n_tiles,
    float* __restrict__ q, float* __restrict__ k, float* __restrict__ v) {
  if ((int)blockIdx.x >= *n_tiles) return;
  int2 td = tile_desc[blockIdx.x];
  int e = td.x, s0 = td.y;
  int seg_end = offsets[e + 1];
  const __bf16* Bt;
  float* dst;
  if (blockIdx.y == 0)      { Bt = pq; dst = q; }
  else if (blockIdx.y == 1) { Bt = pk; dst = k; }
  else                      { Bt = pv; dst = v; }
  Bt += (size_t)e * NH * NC;

  __shared__ __bf16 As[64 * LDA];
  __shared__ __bf16 Bs[128 * LDA];
  int tid = threadIdx.x, lane = tid & 63, wid = tid >> 6, wrow = wid * 16;
  f32x4 acc[8];
#pragma unroll
  for (int i = 0; i < 8; i++) { f32x4 z = {0.f, 0.f, 0.f, 0.f}; acc[i] = z; }

  int tok[4];
#pragma unroll
  for (int i = 0; i < 4; i++) {
    int s = s0 + ((tid + 256 * i) >> 4);
    tok[i] = (s < seg_end) ? slot_token[s] : -1;
  }

  for (int k0 = 0; k0 < NC; k0 += 64) {
#pragma unroll
    for (int i = 0; i < 4; i++) {   // A: gather x rows, fp32->bf16
      int chunk = tid + 256 * i;
      int r = chunk >> 4, c4 = (chunk & 15) * 4;
      bf16x4 ov;
      if (tok[i] >= 0) {
        float4 f = *(const float4*)(x + (size_t)tok[i] * NC + k0 + c4);
        ov[0] = f2bf(f.x); ov[1] = f2bf(f.y); ov[2] = f2bf(f.z); ov[3] = f2bf(f.w);
      } else { ov[0] = ov[1] = ov[2] = ov[3] = (__bf16)0.f; }
      *(bf16x4*)&As[r * LDA + c4] = ov;
    }
#pragma unroll
    for (int i = 0; i < 4; i++) {   // B: P^T rows (pre-transposed bf16)
      int chunk = tid + 256 * i;
      int r = chunk >> 3, c8 = (chunk & 7) * 8;
      *(bf16x8*)&Bs[r * LDA + c8] = *(const bf16x8*)(Bt + (size_t)r * NC + k0 + c8);
    }
    __syncthreads();
    mfma_block(As, Bs, lane, wrow, acc);
    __syncthreads();
  }
  int col = lane & 15, quad = lane >> 4;
#pragma unroll
  for (int r = 0; r < 4; r++) {
    int s = s0 + wrow + quad * 4 + r;
    if (s < seg_end) {
      int tk = slot_token[s];
      float wt = slot_w[s];
#pragma unroll
      for (int nt = 0; nt < 8; nt++)
        atomicAdd(&dst[(size_t)tk * NH + nt * 16 + col], wt * acc[nt][r]);
    }
  }
}

// ---------------- scores = q @ k^T * scale ----------------
__global__ __launch_bounds__(256) void k_scores(const float* __restrict__ q,
                                                const float* __restrict__ k,
                                                float* __restrict__ scores) {
  int b = blockIdx.z;
  int t0 = blockIdx.x * 64;
  int s0 = blockIdx.y * 128;
  const float* qb = q + (size_t)b * NT * NH;
  const float* kb = k + (size_t)b * NT * NH;
  __shared__ __bf16 As[64 * LDA];
  __shared__ __bf16 Bs[128 * LDA];
  int tid = threadIdx.x, lane = tid & 63, wid = tid >> 6, wrow = wid * 16;
  f32x4 acc[8];
#pragma unroll
  for (int i = 0; i < 8; i++) { f32x4 z = {0.f, 0.f, 0.f, 0.f}; acc[i] = z; }

  for (int k0 = 0; k0 < NH; k0 += 64) {
#pragma unroll
    for (int i = 0; i < 4; i++) {
      int chunk = tid + 256 * i;
      int r = chunk >> 4, c4 = (chunk & 15) * 4;
      float4 f = *(const float4*)(qb + (size_t)(t0 + r) * NH + k0 + c4);
      bf16x4 ov; ov[0] = f2bf(f.x); ov[1] = f2bf(f.y); ov[2] = f2bf(f.z); ov[3] = f2bf(f.w);
      *(bf16x4*)&As[r * LDA + c4] = ov;
    }
#pragma unroll
    for (int i = 0; i < 8; i++) {
      int chunk = tid + 256 * i;
      int r = chunk >> 4, c4 = (chunk & 15) * 4;
      float4 f = *(const float4*)(kb + (size_t)(s0 + r) * NH + k0 + c4);
      bf16x4 ov; ov[0] = f2bf(f.x); ov[1] = f2bf(f.y); ov[2] = f2bf(f.z); ov[3] = f2bf(f.w);
      *(bf16x4*)&Bs[r * LDA + c4] = ov;
    }
    __syncthreads();
    mfma_block(As, Bs, lane, wrow, acc);
    __syncthreads();
  }
  const float scale = 0.08838834764831843f;  // 1/sqrt(128)
  int col = lane & 15, quad = lane >> 4;
#pragma unroll
  for (int r = 0; r < 4; r++) {
    size_t row = (size_t)b * NT + t0 + wrow + quad * 4 + r;
#pragma unroll
    for (int nt = 0; nt < 8; nt++)
      scores[row * NT + s0 + nt * 16 + col] = scale * acc[nt][r];
  }
}

// ------- row softmax, in-place: read fp32 row, write bf16 probs over same row -------
__global__ __launch_bounds__(256) void k_softmax(float* __restrict__ scores) {
  int b = blockIdx.y, row = blockIdx.x;
  float* rp = scores + ((size_t)b * NT + row) * NT;
  int t = threadIdx.x;
  float4 v0 = *(const float4*)(rp + t * 8);
  float4 v1 = *(const float4*)(rp + t * 8 + 4);
  float vals[8] = {v0.x, v0.y, v0.z, v0.w, v1.x, v1.y, v1.z, v1.w};
  float m = vals[0];
#pragma unroll
  for (int i = 1; i < 8; i++) m = fmaxf(m, vals[i]);
#pragma unroll
  for (int off = 32; off; off >>= 1) m = fmaxf(m, __shfl_xor(m, off));
  __shared__ float redm[4], reds[4];
  int lane = t & 63, wid = t >> 6;
  if (lane == 0) redm[wid] = m;
  __syncthreads();
  m = fmaxf(fmaxf(redm[0], redm[1]), fmaxf(redm[2], redm[3]));
  float s = 0.f;
#pragma unroll
  for (int i = 0; i < 8; i++) { vals[i] = expf(vals[i] - m); s += vals[i]; }
#pragma unroll
  for (int off = 32; off; off >>= 1) s += __shfl_xor(s, off);
  if (lane == 0) reds[wid] = s;
  __syncthreads();
  s = reds[0] + reds[1] + reds[2] + reds[3];
  float inv = 1.f / s;
  __bf16* op = (__bf16*)rp;
  bf16x4 o0, o1;
#pragma unroll
  for (int i = 0; i < 4; i++) { o0[i] = f2bf(vals[i] * inv); o1[i] = f2bf(vals[4 + i] * inv); }
  *(bf16x4*)(op + t * 8) = o0;
  *(bf16x4*)(op + t * 8 + 4) = o1;
}

// ---------------- o = P @ v  (split-K=4, atomic accumulate) ----------------
__global__ __launch_bounds__(256) void k_av(const char* __restrict__ scores_bytes,
                                            const __bf16* __restrict__ vt,
                                            float* __restrict__ o) {
  int b = blockIdx.z;
  int t0 = blockIdx.x * 64;
  int kc = blockIdx.y;  // K chunk of 512
  __shared__ __bf16 As[64 * LDA];
  __shared__ __bf16 Bs[128 * LDA];
  int tid = threadIdx.x, lane = tid & 63, wid = tid >> 6, wrow = wid * 16;
  f32x4 acc[8];
#pragma unroll
  for (int i = 0; i < 8; i++) { f32x4 z = {0.f, 0.f, 0.f, 0.f}; acc[i] = z; }

  for (int k0 = kc * 512; k0 < kc * 512 + 512; k0 += 64) {
#pragma unroll
    for (int i = 0; i < 2; i++) {   // A: bf16 attn rows (stored at start of fp32 row slots)
      int chunk = tid + 256 * i;
      int r = chunk >> 3, c8 = (chunk & 7) * 8;
      const __bf16* src = (const __bf16*)(scores_bytes + ((size_t)b * NT + t0 + r) * NT * 4) + k0 + c8;
      *(bf16x8*)&As[r * LDA + c8] = *(const bf16x8*)src;
    }
#pragma unroll
    for (int i = 0; i < 4; i++) {   // B: v^T rows [H][T]
      int chunk = tid + 256 * i;
      int r = chunk >> 3, c8 = (chunk & 7) * 8;
      *(bf16x8*)&Bs[r * LDA + c8] = *(const bf16x8*)(vt + ((size_t)b * NH + r) * NT + k0 + c8);
    }
    __syncthreads();
    mfma_block(As, Bs, lane, wrow, acc);
    __syncthreads();
  }
  int col = lane & 15, quad = lane >> 4;
#pragma unroll
  for (int r = 0; r < 4; r++) {
    size_t row = (size_t)b * NT + t0 + wrow + quad * 4 + r;
#pragma unroll
    for (int nt = 0; nt < 8; nt++)
      atomicAdd(&o[row * NH + nt * 16 + col], acc[nt][r]);
  }
}

// ---------------- grouped GEMM: output projection ----------------
__global__ __launch_bounds__(256) void k_out(
    const float* __restrict__ o, const __bf16* __restrict__ pot,
    const int* __restrict__ slot_token, const float* __restrict__ slot_w,
    const int* __restrict__ offsets, const int2* __restrict__ tile_desc,
    const int* __restrict__ n_tiles, float* __restrict__ out) {
  if ((int)blockIdx.x >= *n_tiles) return;
  int2 td = tile_desc[blockIdx.x];
  int e = td.x, s0 = td.y;
  int seg_end = offsets[e + 1];
  int nc0 = blockIdx.y * 128;
  const __bf16* Bt = pot + (size_t)e * NC * NH;

  __shared__ __bf16 As[64 * LDA];
  __shared__ __bf16 Bs[128 * LDA];
  int tid = threadIdx.x, lane = tid & 63, wid = tid >> 6, wrow = wid * 16;
  f32x4 acc[8];
#pragma unroll
  for (int i = 0; i < 8; i++) { f32x4 z = {0.f, 0.f, 0.f, 0.f}; acc[i] = z; }

  int tok[4];
#pragma unroll
  for (int i = 0; i < 4; i++) {
    int s = s0 + ((tid + 256 * i) >> 4);
    tok[i] = (s < seg_end) ? slot_token[s] : -1;
  }

  for (int k0 = 0; k0 < NH; k0 += 64) {
#pragma unroll
    for (int i = 0; i < 4; i++) {   // A: gather o rows fp32->bf16
      int chunk = tid + 256 * i;
      int r = chunk >> 4, c4 = (chunk & 15) * 4;
      bf16x4 ov;
      if (tok[i] >= 0) {
        float4 f = *(const float4*)(o + (size_t)tok[i] * NH + k0 + c4);
        ov[0] = f2bf(f.x); ov[1] = f2bf(f.y); ov[2] = f2bf(f.z); ov[3] = f2bf(f.w);
      } else { ov[0] = ov[1] = ov[2] = ov[3] = (__bf16)0.f; }
      *(bf16x4*)&As[r * LDA + c4] = ov;
    }
#pragma unroll
    for (int i = 0; i < 4; i++) {   // B: o_proj^T rows (pre-transposed bf16)
      int chunk = tid + 256 * i;
      int r = chunk >> 3, c8 = (chunk & 7) * 8;
      *(bf16x8*)&Bs[r * LDA + c8] = *(const bf16x8*)(Bt + (size_t)(nc0 + r) * NH + k0 + c8);
    }
    __syncthreads();
    mfma_block(As, Bs, lane, wrow, acc);
    __syncthreads();
  }
  int col = lane & 15, quad = lane >> 4;
#pragma unroll
  for (int r = 0; r < 4; r++) {
    int s = s0 + wrow + quad * 4 + r;
    if (s < seg_end) {
      int tk = slot_token[s];
      float wt = slot_w[s];
#pragma unroll
      for (int nt = 0; nt < 8; nt++)
        atomicAdd(&out[(size_t)tk * NC + nc0 + nt * 16 + col], wt * acc[nt][r]);
    }
  }
}

extern "C" void kernel_launch(void* const* d_in, const int* in_sizes, int n_in,
                              void* d_out, int out_size, void* d_ws, size_t ws_size,
                              hipStream_t stream) {
  const float* hs    = (const float*)d_in[0];  // [4,2048,1024]
  const float* sim   = (const float*)d_in[1];  // [1024,16]
  const float* gates = (const float*)d_in[2];  // [16]
  const float* qp    = (const float*)d_in[3];  // [16,1024,128]
  const float* kp    = (const float*)d_in[4];
  const float* vp    = (const float*)d_in[5];
  const float* op    = (const float*)d_in[6];  // [16,128,1024]
  float* out = (float*)d_out;
  char* ws = (char*)d_ws;

  // workspace arena (~105 MB)
  const size_t PROJ = (size_t)NE * NC * NH * 2;  // 4 MiB bf16 per proj tensor
  __bf16* PQT = (__bf16*)(ws + 0 * PROJ);
  __bf16* PKT = (__bf16*)(ws + 1 * PROJ);
  __bf16* PVT = (__bf16*)(ws + 2 * PROJ);
  __bf16* POT = (__bf16*)(ws + 3 * PROJ);
  float* Q = (float*)(ws + 16777216);
  float* K = (float*)(ws + 20971520);
  float* V = (float*)(ws + 25165824);
  float* O = (float*)(ws + 29360128);
  __bf16* VT = (__bf16*)(ws + 33554432);
  float* WALL = (float*)(ws + 35651584);
  double* SNORM = (double*)(ws + 36175872);
  int* CNT = (int*)(ws + 36176128);
  int* OFF = CNT + 16;
  int* CUR = CNT + 40;
  int* NTL = CNT + 60;
  int2* DESC = (int2*)(ws + 36176640);
  int* STOK = (int*)(ws + 36193280);
  float* SW = (float*)(ws + 36717568);
  float* SC = (float*)(ws + 37241856);  // 64 MiB fp32 scores / in-place bf16 probs

  hipMemsetAsync(out, 0, (size_t)NTOK * NC * 4, stream);
  hipMemsetAsync(Q, 0, 4ull * 4194304ull, stream);  // Q,K,V,O contiguous
  hipMemsetAsync(CNT, 0, 512, stream);

  k_colnorm<<<NE, 256, 0, stream>>>(sim, SNORM);
  k_transpose<<<dim3(32, 4, 16), 256, 0, stream>>>(qp, PQT, 1024, 128);
  k_transpose<<<dim3(32, 4, 16), 256, 0, stream>>>(kp, PKT, 1024, 128);
  k_transpose<<<dim3(32, 4, 16), 256, 0, stream>>>(vp, PVT, 1024, 128);
  k_transpose<<<dim3(4, 32, 16), 256, 0, stream>>>(op, POT, 128, 1024);
  k_gating<<<NTOK, 256, 0, stream>>>(hs, sim, gates, SNORM, WALL, CNT);
  k_scan<<<1, 64, 0, stream>>>(CNT, OFF, DESC, NTL);
  k_assign<<<NTOK / 256, 256, 0, stream>>>(WALL, OFF, CUR, STOK, SW);
  k_moe_qkv<<<dim3(MAXTILES, 3), 256, 0, stream>>>(hs, PQT, PKT, PVT, STOK, SW, OFF, DESC, NTL, Q, K, V);
  k_scores<<<dim3(32, 16, 4), 256, 0, stream>>>(Q, K, SC);
  k_softmax<<<dim3(2048, 4), 256, 0, stream>>>(SC);
  k_transpose<<<dim3(64, 4, 4), 256, 0, stream>>>(V, VT, 2048, 128);
  k_av<<<dim3(32, 4, 4), 256, 0, stream>>>((const char*)SC, VT, O);
  k_out<<<dim3(MAXTILES, 8), 256, 0, stream>>>(O, POT, STOK, SW, OFF, DESC, NTL, out);
}

// Round 2
// 414.445 us; speedup vs baseline: 1.3795x; 1.3795x over previous
//
#include <hip/hip_runtime.h>
#include <hip/hip_bf16.h>
#include <math.h>

// DynSMHA: B=4 T=2048 C=1024 H=128 E=16 MIN_E=2, non-causal.
// Pipeline: fp64 gating (lane-per-expert, no reduction) -> expert bucketing ->
// grouped bf16-MFMA GEMMs (QKV, scores, PV, out-proj) with fp32 accumulation.
#define NBATCH 4
#define NT     2048
#define NC     1024
#define NH     128
#define NE     16
#define NTOK   (NBATCH * NT)
#define LDA    72            // LDS leading dim (64 + 8 bf16 pad -> conflict-free)
#define MAXTILES 2064        // worst case sum ceil(cnt_e/64) = 16 + 131072/64
#define SIMLD  1028          // sim^T LDS row stride (floats): %32==4 -> 2-way only (free)

typedef __bf16 bf16x8 __attribute__((ext_vector_type(8)));
typedef __bf16 bf16x4 __attribute__((ext_vector_type(4)));
typedef float  f32x4  __attribute__((ext_vector_type(4)));

__device__ __forceinline__ __bf16 f2bf(float f) { return (__bf16)f; }

// ---------------- prep: sim column norms + sigmoid(gates), fp64, one block ----------------
__global__ void k_prep(const float* __restrict__ sim, const float* __restrict__ gates,
                       double* __restrict__ snorm, double* __restrict__ sig) {
  int tid = threadIdx.x;
  int e = tid & 15, chunk = tid >> 4;
  double a = 0.0;
#pragma unroll 4
  for (int j = 0; j < 64; j++) {
    double v = (double)sim[(chunk * 64 + j) * NE + e];
    a += v * v;
  }
  __shared__ double red[16][17];
  red[chunk][e] = a;
  __syncthreads();
  if (tid < 16) {
    double s = 0.0;
    for (int k = 0; k < 16; k++) s += red[k][tid];
    snorm[tid] = fmax(sqrt(s), 1e-12);
    sig[tid] = 1.0 / (1.0 + exp(-(double)gates[tid]));
  }
}

// ---------------- gating v2: lane = (expert, token-subgroup); no cross-lane reduce ----------------
__global__ __launch_bounds__(256) void k_gating2(const float* __restrict__ x,
                                                 const float* __restrict__ sim,
                                                 const double* __restrict__ snorm,
                                                 const double* __restrict__ sig,
                                                 float* __restrict__ w_all,
                                                 int* __restrict__ counts) {
  __shared__ float sim_lds[16 * SIMLD];
  __shared__ double dot_lds[16][17];
  __shared__ double norm_lds[16];
  __shared__ float w_lds[16][16];
  __shared__ int cnt_lds[16];
  int tid = threadIdx.x;
  // stage sim^T into LDS: sim_lds[e][c] = sim[c][e]
#pragma unroll 8
  for (int k = 0; k < 64; k++) {
    int i = k * 256 + tid;
    sim_lds[(i & 15) * SIMLD + (i >> 4)] = sim[i];
  }
  if (tid < 16) cnt_lds[tid] = 0;
  __syncthreads();

  int lane = tid & 63, wv = tid >> 6;
  int e = lane & 15, tg = lane >> 4;
  int trow = wv * 4 + tg;                       // 0..15 within block
  int token = blockIdx.x * 16 + trow;
  const float4* xr = (const float4*)(x + (size_t)token * NC);  // broadcast across 16 lanes
  const float4* sr = (const float4*)(sim_lds + e * SIMLD);
  double d0 = 0.0, d1 = 0.0, n0 = 0.0, n1 = 0.0;
#pragma unroll 4
  for (int c4 = 0; c4 < NC / 4; c4++) {
    float4 xv = xr[c4];
    float4 sv = sr[c4];
    d0 += (double)xv.x * (double)sv.x;
    d1 += (double)xv.y * (double)sv.y;
    d0 += (double)xv.z * (double)sv.z;
    d1 += (double)xv.w * (double)sv.w;
    n0 += (double)xv.x * (double)xv.x;
    n1 += (double)xv.y * (double)xv.y;
    n0 += (double)xv.z * (double)xv.z;
    n1 += (double)xv.w * (double)xv.w;
  }
  dot_lds[trow][e] = d0 + d1;
  if (e == 0) norm_lds[trow] = n0 + n1;
  __syncthreads();

  if (tid < 16) {  // one thread per token: act-set / fallback / softmax
    double xn = fmax(sqrt(norm_lds[tid]), 1e-12);
    double logits[NE];
    unsigned act = 0;
    int cnt = 0;
    for (int ee = 0; ee < NE; ee++) {
      logits[ee] = dot_lds[tid][ee] / (xn * snorm[ee]) - sig[ee];
      if (logits[ee] > 0.0) { act |= 1u << ee; cnt++; }
    }
    if (cnt == 0) {  // fallback: top-MIN_E(=2) logits, jax.top_k tie-break = lowest index
      int i1 = 0; double b1 = logits[0];
      for (int ee = 1; ee < NE; ee++) if (logits[ee] > b1) { b1 = logits[ee]; i1 = ee; }
      int i2 = -1; double b2 = -1e300;
      for (int ee = 0; ee < NE; ee++) if (ee != i1 && logits[ee] > b2) { b2 = logits[ee]; i2 = ee; }
      act = (1u << i1) | (1u << i2);
    }
    double m = -1e300;
    for (int ee = 0; ee < NE; ee++) if ((act >> ee) & 1) m = fmax(m, fmax(logits[ee], 0.0));
    double s = 0.0, wvv[NE];
    for (int ee = 0; ee < NE; ee++) {
      if ((act >> ee) & 1) { wvv[ee] = exp(fmax(logits[ee], 0.0) - m); s += wvv[ee]; }
      else wvv[ee] = 0.0;
    }
    for (int ee = 0; ee < NE; ee++) {
      if ((act >> ee) & 1) {
        w_lds[tid][ee] = (float)(wvv[ee] / s);
        atomicAdd(&cnt_lds[ee], 1);
      } else w_lds[tid][ee] = 0.0f;
    }
  }
  __syncthreads();
  w_all[(size_t)(blockIdx.x * 16 + (tid >> 4)) * NE + (tid & 15)] = w_lds[tid >> 4][tid & 15];
  if (tid < 16 && cnt_lds[tid] > 0) atomicAdd(&counts[tid], cnt_lds[tid]);
}

// ------- transpose last two dims, fp32 -> bf16: in[G][R][Cd] -> out[G][Cd][R] -------
__global__ void k_transpose(const float* __restrict__ in, __bf16* __restrict__ out, int R, int Cd) {
  __shared__ float tile[32][33];
  int g = blockIdx.z;
  int r0 = blockIdx.x * 32, c0 = blockIdx.y * 32;
  int tx = threadIdx.x & 31, ty0 = threadIdx.x >> 5;
  const float* src = in + (size_t)g * R * Cd;
  __bf16* dst = out + (size_t)g * R * Cd;
#pragma unroll
  for (int ty = ty0; ty < 32; ty += 8)
    tile[ty][tx] = src[(size_t)(r0 + ty) * Cd + (c0 + tx)];
  __syncthreads();
#pragma unroll
  for (int ty = ty0; ty < 32; ty += 8)
    dst[(size_t)(c0 + ty) * R + (r0 + tx)] = f2bf(tile[tx][ty]);
}

// ---------------- scan counts -> offsets + tile descriptors ----------------
__global__ void k_scan(const int* __restrict__ counts, int* __restrict__ offsets,
                       int2* __restrict__ tile_desc, int* __restrict__ n_tiles) {
  if (threadIdx.x == 0 && blockIdx.x == 0) {
    int off = 0, nt = 0;
    for (int e = 0; e < NE; e++) {
      offsets[e] = off;
      int c = counts[e];
      int tiles = (c + 63) >> 6;
      for (int t = 0; t < tiles; t++) { tile_desc[nt].x = e; tile_desc[nt].y = off + t * 64; nt++; }
      off += c;
    }
    offsets[NE] = off;
    *n_tiles = nt;
  }
}

// ---------------- slot assignment ----------------
__global__ void k_assign(const float* __restrict__ w_all, const int* __restrict__ offsets,
                         int* __restrict__ cursors, int* __restrict__ slot_token,
                         float* __restrict__ slot_w) {
  int n = blockIdx.x * 256 + threadIdx.x;
  if (n >= NTOK) return;
  for (int e = 0; e < NE; e++) {
    float w = w_all[(size_t)n * NE + e];
    if (w > 0.0f) {
      int p = atomicAdd(&cursors[e], 1);
      int s = offsets[e] + p;
      slot_token[s] = n;
      slot_w[s] = w;
    }
  }
}

// ---------------- shared MFMA inner tile: 64x128, BK=64 ----------------
__device__ __forceinline__ void mfma_block(const __bf16* As, const __bf16* Bs,
                                           int lane, int wrow, f32x4 acc[8]) {
#pragma unroll
  for (int ks = 0; ks < 2; ks++) {
    int koff = ks * 32 + (lane >> 4) * 8;
    bf16x8 af = *(const bf16x8*)&As[(wrow + (lane & 15)) * LDA + koff];
#pragma unroll
    for (int nt = 0; nt < 8; nt++) {
      bf16x8 bv = *(const bf16x8*)&Bs[(nt * 16 + (lane & 15)) * LDA + koff];
      acc[nt] = __builtin_amdgcn_mfma_f32_16x16x32_bf16(af, bv, acc[nt], 0, 0, 0);
    }
  }
}

// ---------------- grouped GEMM: QKV projections ----------------
__global__ __launch_bounds__(256) void k_moe_qkv(
    const float* __restrict__ x,
    const __bf16* __restrict__ pq, const __bf16* __restrict__ pk, const __bf16* __restrict__ pv,
    const int* __restrict__ slot_token, const float* __restrict__ slot_w,
    const int* __restrict__ offsets, const int2* __restrict__ tile_desc,
    const int* __restrict__ n_tiles,
    float* __restrict__ q, float* __restrict__ k, float* __restrict__ v) {
  if ((int)blockIdx.x >= *n_tiles) return;
  int2 td = tile_desc[blockIdx.x];
  int e = td.x, s0 = td.y;
  int seg_end = offsets[e + 1];
  const __bf16* Bt;
  float* dst;
  if (blockIdx.y == 0)      { Bt = pq; dst = q; }
  else if (blockIdx.y == 1) { Bt = pk; dst = k; }
  else                      { Bt = pv; dst = v; }
  Bt += (size_t)e * NH * NC;

  __shared__ __bf16 As[64 * LDA];
  __shared__ __bf16 Bs[128 * LDA];
  int tid = threadIdx.x, lane = tid & 63, wid = tid >> 6, wrow = wid * 16;
  f32x4 acc[8];
#pragma unroll
  for (int i = 0; i < 8; i++) { f32x4 z = {0.f, 0.f, 0.f, 0.f}; acc[i] = z; }

  int tok[4];
#pragma unroll
  for (int i = 0; i < 4; i++) {
    int s = s0 + ((tid + 256 * i) >> 4);
    tok[i] = (s < seg_end) ? slot_token[s] : -1;
  }

  for (int k0 = 0; k0 < NC; k0 += 64) {
#pragma unroll
    for (int i = 0; i < 4; i++) {   // A: gather x rows, fp32->bf16
      int chunk = tid + 256 * i;
      int r = chunk >> 4, c4 = (chunk & 15) * 4;
      bf16x4 ov;
      if (tok[i] >= 0) {
        float4 f = *(const float4*)(x + (size_t)tok[i] * NC + k0 + c4);
        ov[0] = f2bf(f.x); ov[1] = f2bf(f.y); ov[2] = f2bf(f.z); ov[3] = f2bf(f.w);
      } else { ov[0] = ov[1] = ov[2] = ov[3] = (__bf16)0.f; }
      *(bf16x4*)&As[r * LDA + c4] = ov;
    }
#pragma unroll
    for (int i = 0; i < 4; i++) {   // B: P^T rows (pre-transposed bf16)
      int chunk = tid + 256 * i;
      int r = chunk >> 3, c8 = (chunk & 7) * 8;
      *(bf16x8*)&Bs[r * LDA + c8] = *(const bf16x8*)(Bt + (size_t)r * NC + k0 + c8);
    }
    __syncthreads();
    mfma_block(As, Bs, lane, wrow, acc);
    __syncthreads();
  }
  int col = lane & 15, quad = lane >> 4;
#pragma unroll
  for (int r = 0; r < 4; r++) {
    int s = s0 + wrow + quad * 4 + r;
    if (s < seg_end) {
      int tk = slot_token[s];
      float wt = slot_w[s];
#pragma unroll
      for (int nt = 0; nt < 8; nt++)
        atomicAdd(&dst[(size_t)tk * NH + nt * 16 + col], wt * acc[nt][r]);
    }
  }
}

// ---------------- scores = q @ k^T * scale ----------------
__global__ __launch_bounds__(256) void k_scores(const float* __restrict__ q,
                                                const float* __restrict__ k,
                                                float* __restrict__ scores) {
  int b = blockIdx.z;
  int t0 = blockIdx.x * 64;
  int s0 = blockIdx.y * 128;
  const float* qb = q + (size_t)b * NT * NH;
  const float* kb = k + (size_t)b * NT * NH;
  __shared__ __bf16 As[64 * LDA];
  __shared__ __bf16 Bs[128 * LDA];
  int tid = threadIdx.x, lane = tid & 63, wid = tid >> 6, wrow = wid * 16;
  f32x4 acc[8];
#pragma unroll
  for (int i = 0; i < 8; i++) { f32x4 z = {0.f, 0.f, 0.f, 0.f}; acc[i] = z; }

  for (int k0 = 0; k0 < NH; k0 += 64) {
#pragma unroll
    for (int i = 0; i < 4; i++) {
      int chunk = tid + 256 * i;
      int r = chunk >> 4, c4 = (chunk & 15) * 4;
      float4 f = *(const float4*)(qb + (size_t)(t0 + r) * NH + k0 + c4);
      bf16x4 ov; ov[0] = f2bf(f.x); ov[1] = f2bf(f.y); ov[2] = f2bf(f.z); ov[3] = f2bf(f.w);
      *(bf16x4*)&As[r * LDA + c4] = ov;
    }
#pragma unroll
    for (int i = 0; i < 8; i++) {
      int chunk = tid + 256 * i;
      int r = chunk >> 4, c4 = (chunk & 15) * 4;
      float4 f = *(const float4*)(kb + (size_t)(s0 + r) * NH + k0 + c4);
      bf16x4 ov; ov[0] = f2bf(f.x); ov[1] = f2bf(f.y); ov[2] = f2bf(f.z); ov[3] = f2bf(f.w);
      *(bf16x4*)&Bs[r * LDA + c4] = ov;
    }
    __syncthreads();
    mfma_block(As, Bs, lane, wrow, acc);
    __syncthreads();
  }
  const float scale = 0.08838834764831843f;  // 1/sqrt(128)
  int col = lane & 15, quad = lane >> 4;
#pragma unroll
  for (int r = 0; r < 4; r++) {
    size_t row = (size_t)b * NT + t0 + wrow + quad * 4 + r;
#pragma unroll
    for (int nt = 0; nt < 8; nt++)
      scores[row * NT + s0 + nt * 16 + col] = scale * acc[nt][r];
  }
}

// ------- row softmax, in-place: read fp32 row, write bf16 probs over same row -------
__global__ __launch_bounds__(256) void k_softmax(float* __restrict__ scores) {
  int b = blockIdx.y, row = blockIdx.x;
  float* rp = scores + ((size_t)b * NT + row) * NT;
  int t = threadIdx.x;
  float4 v0 = *(const float4*)(rp + t * 8);
  float4 v1 = *(const float4*)(rp + t * 8 + 4);
  float vals[8] = {v0.x, v0.y, v0.z, v0.w, v1.x, v1.y, v1.z, v1.w};
  float m = vals[0];
#pragma unroll
  for (int i = 1; i < 8; i++) m = fmaxf(m, vals[i]);
#pragma unroll
  for (int off = 32; off; off >>= 1) m = fmaxf(m, __shfl_xor(m, off));
  __shared__ float redm[4], reds[4];
  int lane = t & 63, wid = t >> 6;
  if (lane == 0) redm[wid] = m;
  __syncthreads();
  m = fmaxf(fmaxf(redm[0], redm[1]), fmaxf(redm[2], redm[3]));
  float s = 0.f;
#pragma unroll
  for (int i = 0; i < 8; i++) { vals[i] = expf(vals[i] - m); s += vals[i]; }
#pragma unroll
  for (int off = 32; off; off >>= 1) s += __shfl_xor(s, off);
  if (lane == 0) reds[wid] = s;
  __syncthreads();
  s = reds[0] + reds[1] + reds[2] + reds[3];
  float inv = 1.f / s;
  __bf16* op = (__bf16*)rp;
  bf16x4 o0, o1;
#pragma unroll
  for (int i = 0; i < 4; i++) { o0[i] = f2bf(vals[i] * inv); o1[i] = f2bf(vals[4 + i] * inv); }
  *(bf16x4*)(op + t * 8) = o0;
  *(bf16x4*)(op + t * 8 + 4) = o1;
}

// ---------------- o = P @ v  (split-K=4, atomic accumulate) ----------------
__global__ __launch_bounds__(256) void k_av(const char* __restrict__ scores_bytes,
                                            const __bf16* __restrict__ vt,
                                            float* __restrict__ o) {
  int b = blockIdx.z;
  int t0 = blockIdx.x * 64;
  int kc = blockIdx.y;  // K chunk of 512
  __shared__ __bf16 As[64 * LDA];
  __shared__ __bf16 Bs[128 * LDA];
  int tid = threadIdx.x, lane = tid & 63, wid = tid >> 6, wrow = wid * 16;
  f32x4 acc[8];
#pragma unroll
  for (int i = 0; i < 8; i++) { f32x4 z = {0.f, 0.f, 0.f, 0.f}; acc[i] = z; }

  for (int k0 = kc * 512; k0 < kc * 512 + 512; k0 += 64) {
#pragma unroll
    for (int i = 0; i < 2; i++) {   // A: bf16 attn rows (stored at start of fp32 row slots)
      int chunk = tid + 256 * i;
      int r = chunk >> 3, c8 = (chunk & 7) * 8;
      const __bf16* src = (const __bf16*)(scores_bytes + ((size_t)b * NT + t0 + r) * NT * 4) + k0 + c8;
      *(bf16x8*)&As[r * LDA + c8] = *(const bf16x8*)src;
    }
#pragma unroll
    for (int i = 0; i < 4; i++) {   // B: v^T rows [H][T]
      int chunk = tid + 256 * i;
      int r = chunk >> 3, c8 = (chunk & 7) * 8;
      *(bf16x8*)&Bs[r * LDA + c8] = *(const bf16x8*)(vt + ((size_t)b * NH + r) * NT + k0 + c8);
    }
    __syncthreads();
    mfma_block(As, Bs, lane, wrow, acc);
    __syncthreads();
  }
  int col = lane & 15, quad = lane >> 4;
#pragma unroll
  for (int r = 0; r < 4; r++) {
    size_t row = (size_t)b * NT + t0 + wrow + quad * 4 + r;
#pragma unroll
    for (int nt = 0; nt < 8; nt++)
      atomicAdd(&o[row * NH + nt * 16 + col], acc[nt][r]);
  }
}

// ---------------- grouped GEMM: output projection ----------------
__global__ __launch_bounds__(256) void k_out(
    const float* __restrict__ o, const __bf16* __restrict__ pot,
    const int* __restrict__ slot_token, const float* __restrict__ slot_w,
    const int* __restrict__ offsets, const int2* __restrict__ tile_desc,
    const int* __restrict__ n_tiles, float* __restrict__ out) {
  if ((int)blockIdx.x >= *n_tiles) return;
  int2 td = tile_desc[blockIdx.x];
  int e = td.x, s0 = td.y;
  int seg_end = offsets[e + 1];
  int nc0 = blockIdx.y * 128;
  const __bf16* Bt = pot + (size_t)e * NC * NH;

  __shared__ __bf16 As[64 * LDA];
  __shared__ __bf16 Bs[128 * LDA];
  int tid = threadIdx.x, lane = tid & 63, wid = tid >> 6, wrow = wid * 16;
  f32x4 acc[8];
#pragma unroll
  for (int i = 0; i < 8; i++) { f32x4 z = {0.f, 0.f, 0.f, 0.f}; acc[i] = z; }

  int tok[4];
#pragma unroll
  for (int i = 0; i < 4; i++) {
    int s = s0 + ((tid + 256 * i) >> 4);
    tok[i] = (s < seg_end) ? slot_token[s] : -1;
  }

  for (int k0 = 0; k0 < NH; k0 += 64) {
#pragma unroll
    for (int i = 0; i < 4; i++) {   // A: gather o rows fp32->bf16
      int chunk = tid + 256 * i;
      int r = chunk >> 4, c4 = (chunk & 15) * 4;
      bf16x4 ov;
      if (tok[i] >= 0) {
        float4 f = *(const float4*)(o + (size_t)tok[i] * NH + k0 + c4);
        ov[0] = f2bf(f.x); ov[1] = f2bf(f.y); ov[2] = f2bf(f.z); ov[3] = f2bf(f.w);
      } else { ov[0] = ov[1] = ov[2] = ov[3] = (__bf16)0.f; }
      *(bf16x4*)&As[r * LDA + c4] = ov;
    }
#pragma unroll
    for (int i = 0; i < 4; i++) {   // B: o_proj^T rows (pre-transposed bf16)
      int chunk = tid + 256 * i;
      int r = chunk >> 3, c8 = (chunk & 7) * 8;
      *(bf16x8*)&Bs[r * LDA + c8] = *(const bf16x8*)(Bt + (size_t)(nc0 + r) * NH + k0 + c8);
    }
    __syncthreads();
    mfma_block(As, Bs, lane, wrow, acc);
    __syncthreads();
  }
  int col = lane & 15, quad = lane >> 4;
#pragma unroll
  for (int r = 0; r < 4; r++) {
    int s = s0 + wrow + quad * 4 + r;
    if (s < seg_end) {
      int tk = slot_token[s];
      float wt = slot_w[s];
#pragma unroll
      for (int nt = 0; nt < 8; nt++)
        atomicAdd(&out[(size_t)tk * NC + nc0 + nt * 16 + col], wt * acc[nt][r]);
    }
  }
}

extern "C" void kernel_launch(void* const* d_in, const int* in_sizes, int n_in,
                              void* d_out, int out_size, void* d_ws, size_t ws_size,
                              hipStream_t stream) {
  const float* hs    = (const float*)d_in[0];  // [4,2048,1024]
  const float* sim   = (const float*)d_in[1];  // [1024,16]
  const float* gates = (const float*)d_in[2];  // [16]
  const float* qp    = (const float*)d_in[3];  // [16,1024,128]
  const float* kp    = (const float*)d_in[4];
  const float* vp    = (const float*)d_in[5];
  const float* op    = (const float*)d_in[6];  // [16,128,1024]
  float* out = (float*)d_out;
  char* ws = (char*)d_ws;

  // workspace arena (~105 MB)
  const size_t PROJ = (size_t)NE * NC * NH * 2;  // 4 MiB bf16 per proj tensor
  __bf16* PQT = (__bf16*)(ws + 0 * PROJ);
  __bf16* PKT = (__bf16*)(ws + 1 * PROJ);
  __bf16* PVT = (__bf16*)(ws + 2 * PROJ);
  __bf16* POT = (__bf16*)(ws + 3 * PROJ);
  float* Q = (float*)(ws + 16777216);
  float* K = (float*)(ws + 20971520);
  float* V = (float*)(ws + 25165824);
  float* O = (float*)(ws + 29360128);
  __bf16* VT = (__bf16*)(ws + 33554432);
  float* WALL = (float*)(ws + 35651584);
  double* SNORM = (double*)(ws + 36175872);    // 16 doubles
  double* SIG   = SNORM + 16;                  // 16 doubles
  int* CNT = (int*)(ws + 36176128);
  int* OFF = CNT + 16;
  int* CUR = CNT + 40;
  int* NTL = CNT + 60;
  int2* DESC = (int2*)(ws + 36176640);
  int* STOK = (int*)(ws + 36193280);
  float* SW = (float*)(ws + 36717568);
  float* SC = (float*)(ws + 37241856);  // 64 MiB fp32 scores / in-place bf16 probs

  hipMemsetAsync(out, 0, (size_t)NTOK * NC * 4, stream);
  hipMemsetAsync(Q, 0, 4ull * 4194304ull, stream);  // Q,K,V,O contiguous
  hipMemsetAsync(CNT, 0, 512, stream);

  k_prep<<<1, 256, 0, stream>>>(sim, gates, SNORM, SIG);
  k_transpose<<<dim3(32, 4, 16), 256, 0, stream>>>(qp, PQT, 1024, 128);
  k_transpose<<<dim3(32, 4, 16), 256, 0, stream>>>(kp, PKT, 1024, 128);
  k_transpose<<<dim3(32, 4, 16), 256, 0, stream>>>(vp, PVT, 1024, 128);
  k_transpose<<<dim3(4, 32, 16), 256, 0, stream>>>(op, POT, 128, 1024);
  k_gating2<<<NTOK / 16, 256, 0, stream>>>(hs, sim, SNORM, SIG, WALL, CNT);
  k_scan<<<1, 64, 0, stream>>>(CNT, OFF, DESC, NTL);
  k_assign<<<NTOK / 256, 256, 0, stream>>>(WALL, OFF, CUR, STOK, SW);
  k_moe_qkv<<<dim3(MAXTILES, 3), 256, 0, stream>>>(hs, PQT, PKT, PVT, STOK, SW, OFF, DESC, NTL, Q, K, V);
  k_scores<<<dim3(32, 16, 4), 256, 0, stream>>>(Q, K, SC);
  k_softmax<<<dim3(2048, 4), 256, 0, stream>>>(SC);
  k_transpose<<<dim3(64, 4, 4), 256, 0, stream>>>(V, VT, 2048, 128);
  k_av<<<dim3(32, 4, 4), 256, 0, stream>>>((const char*)SC, VT, O);
  k_out<<<dim3(MAXTILES, 8), 256, 0, stream>>>(O, POT, STOK, SW, OFF, DESC, NTL, out);
}

// Round 3
// 387.747 us; speedup vs baseline: 1.4745x; 1.0689x over previous
//
#include <hip/hip_runtime.h>
#include <hip/hip_bf16.h>
#include <math.h>

// DynSMHA: B=4 T=2048 C=1024 H=128 E=16 MIN_E=2, non-causal.
// fp64 gating -> slot bucketing (+token->slot inverse map) -> pre-gathered
// bf16 grouped GEMMs (slot-major, no scatter atomics) -> per-token combines.
#define NBATCH 4
#define NT     2048
#define NC     1024
#define NH     128
#define NE     16
#define NTOK   (NBATCH * NT)
#define LDA    72            // LDS leading dim (64 + 8 bf16 pad)
#define SIMLD  1028
#define CAP    18432         // slot capacity for gathered buffers (actual ~16384)
#define XGROWS (CAP + 64)
#define NTILE_MAX 304        // sum ceil(cnt_e/64) clamped at CAP

typedef __bf16 bf16x8 __attribute__((ext_vector_type(8)));
typedef __bf16 bf16x4 __attribute__((ext_vector_type(4)));
typedef float  f32x4  __attribute__((ext_vector_type(4)));

__device__ __forceinline__ __bf16 f2bf(float f) { return (__bf16)f; }

// ---------------- prep: sim column norms + sigmoid(gates), fp64 ----------------
__global__ void k_prep(const float* __restrict__ sim, const float* __restrict__ gates,
                       double* __restrict__ snorm, double* __restrict__ sig) {
  int tid = threadIdx.x;
  int e = tid & 15, chunk = tid >> 4;
  double a = 0.0;
#pragma unroll 4
  for (int j = 0; j < 64; j++) {
    double v = (double)sim[(chunk * 64 + j) * NE + e];
    a += v * v;
  }
  __shared__ double red[16][17];
  red[chunk][e] = a;
  __syncthreads();
  if (tid < 16) {
    double s = 0.0;
    for (int k = 0; k < 16; k++) s += red[k][tid];
    snorm[tid] = fmax(sqrt(s), 1e-12);
    sig[tid] = 1.0 / (1.0 + exp(-(double)gates[tid]));
  }
}

// ---------------- gating: lane = (expert, token-subgroup) ----------------
__global__ __launch_bounds__(256) void k_gating2(const float* __restrict__ x,
                                                 const float* __restrict__ sim,
                                                 const double* __restrict__ snorm,
                                                 const double* __restrict__ sig,
                                                 float* __restrict__ w_all,
                                                 int* __restrict__ counts) {
  __shared__ float sim_lds[16 * SIMLD];
  __shared__ double dot_lds[16][17];
  __shared__ double norm_lds[16];
  __shared__ float w_lds[16][16];
  __shared__ int cnt_lds[16];
  int tid = threadIdx.x;
#pragma unroll 8
  for (int k = 0; k < 64; k++) {
    int i = k * 256 + tid;
    sim_lds[(i & 15) * SIMLD + (i >> 4)] = sim[i];
  }
  if (tid < 16) cnt_lds[tid] = 0;
  __syncthreads();

  int lane = tid & 63, wv = tid >> 6;
  int e = lane & 15, tg = lane >> 4;
  int trow = wv * 4 + tg;
  int token = blockIdx.x * 16 + trow;
  const float4* xr = (const float4*)(x + (size_t)token * NC);
  const float4* sr = (const float4*)(sim_lds + e * SIMLD);
  double d0 = 0.0, d1 = 0.0, n0 = 0.0, n1 = 0.0;
#pragma unroll 4
  for (int c4 = 0; c4 < NC / 4; c4++) {
    float4 xv = xr[c4];
    float4 sv = sr[c4];
    d0 += (double)xv.x * (double)sv.x;
    d1 += (double)xv.y * (double)sv.y;
    d0 += (double)xv.z * (double)sv.z;
    d1 += (double)xv.w * (double)sv.w;
    n0 += (double)xv.x * (double)xv.x;
    n1 += (double)xv.y * (double)xv.y;
    n0 += (double)xv.z * (double)xv.z;
    n1 += (double)xv.w * (double)xv.w;
  }
  dot_lds[trow][e] = d0 + d1;
  if (e == 0) norm_lds[trow] = n0 + n1;
  __syncthreads();

  if (tid < 16) {
    double xn = fmax(sqrt(norm_lds[tid]), 1e-12);
    double logits[NE];
    unsigned act = 0;
    int cnt = 0;
    for (int ee = 0; ee < NE; ee++) {
      logits[ee] = dot_lds[tid][ee] / (xn * snorm[ee]) - sig[ee];
      if (logits[ee] > 0.0) { act |= 1u << ee; cnt++; }
    }
    if (cnt == 0) {  // top-MIN_E(=2) fallback, lowest-index tie-break
      int i1 = 0; double b1 = logits[0];
      for (int ee = 1; ee < NE; ee++) if (logits[ee] > b1) { b1 = logits[ee]; i1 = ee; }
      int i2 = -1; double b2 = -1e300;
      for (int ee = 0; ee < NE; ee++) if (ee != i1 && logits[ee] > b2) { b2 = logits[ee]; i2 = ee; }
      act = (1u << i1) | (1u << i2);
    }
    double m = -1e300;
    for (int ee = 0; ee < NE; ee++) if ((act >> ee) & 1) m = fmax(m, fmax(logits[ee], 0.0));
    double s = 0.0, wvv[NE];
    for (int ee = 0; ee < NE; ee++) {
      if ((act >> ee) & 1) { wvv[ee] = exp(fmax(logits[ee], 0.0) - m); s += wvv[ee]; }
      else wvv[ee] = 0.0;
    }
    for (int ee = 0; ee < NE; ee++) {
      if ((act >> ee) & 1) {
        w_lds[tid][ee] = (float)(wvv[ee] / s);
        atomicAdd(&cnt_lds[ee], 1);
      } else w_lds[tid][ee] = 0.0f;
    }
  }
  __syncthreads();
  w_all[(size_t)(blockIdx.x * 16 + (tid >> 4)) * NE + (tid & 15)] = w_lds[tid >> 4][tid & 15];
  if (tid < 16 && cnt_lds[tid] > 0) atomicAdd(&counts[tid], cnt_lds[tid]);
}

// ------- transpose last two dims, fp32 -> bf16 (weights) -------
__global__ void k_transpose(const float* __restrict__ in, __bf16* __restrict__ out, int R, int Cd) {
  __shared__ float tile[32][33];
  int g = blockIdx.z;
  int r0 = blockIdx.x * 32, c0 = blockIdx.y * 32;
  int tx = threadIdx.x & 31, ty0 = threadIdx.x >> 5;
  const float* src = in + (size_t)g * R * Cd;
  __bf16* dst = out + (size_t)g * R * Cd;
#pragma unroll
  for (int ty = ty0; ty < 32; ty += 8)
    tile[ty][tx] = src[(size_t)(r0 + ty) * Cd + (c0 + tx)];
  __syncthreads();
#pragma unroll
  for (int ty = ty0; ty < 32; ty += 8)
    dst[(size_t)(c0 + ty) * R + (r0 + tx)] = f2bf(tile[tx][ty]);
}

// ------- transpose bf16 -> bf16: V [g][R][Cd] -> VT [g][Cd][R] -------
__global__ void k_transpose_bf(const __bf16* __restrict__ in, __bf16* __restrict__ out,
                               int R, int Cd) {
  __shared__ __bf16 tile[32][34];
  int g = blockIdx.z;
  int r0 = blockIdx.x * 32, c0 = blockIdx.y * 32;
  int tx = threadIdx.x & 31, ty0 = threadIdx.x >> 5;
  const __bf16* src = in + (size_t)g * R * Cd;
  __bf16* dst = out + (size_t)g * R * Cd;
#pragma unroll
  for (int ty = ty0; ty < 32; ty += 8)
    tile[ty][tx] = src[(size_t)(r0 + ty) * Cd + (c0 + tx)];
  __syncthreads();
#pragma unroll
  for (int ty = ty0; ty < 32; ty += 8)
    dst[(size_t)(c0 + ty) * R + (r0 + tx)] = tile[tx][ty];
}

// ---------------- scan counts -> offsets + tile descriptors (clamped) ----------------
__global__ void k_scan(const int* __restrict__ counts, int* __restrict__ offsets,
                       int2* __restrict__ tile_desc, int* __restrict__ n_tiles) {
  if (threadIdx.x == 0 && blockIdx.x == 0) {
    int off = 0, nt = 0;
    for (int e = 0; e < NE; e++) {
      offsets[e] = off;
      int c = counts[e];
      int tiles = (c + 63) >> 6;
      for (int t = 0; t < tiles; t++) {
        int s0 = off + t * 64;
        if (s0 < CAP && nt < NTILE_MAX) { tile_desc[nt].x = e; tile_desc[nt].y = s0; nt++; }
      }
      off += c;
    }
    offsets[NE] = off;
    *n_tiles = nt;
  }
}

// ---------------- slot assignment + token->slot inverse map ----------------
__global__ void k_assign(const float* __restrict__ w_all, const int* __restrict__ offsets,
                         int* __restrict__ cursors, int* __restrict__ slot_token,
                         float* __restrict__ slot_w, int* __restrict__ tok_slots,
                         int* __restrict__ tok_cnt) {
  int n = blockIdx.x * 256 + threadIdx.x;
  if (n >= NTOK) return;
  int j = 0;
  for (int e = 0; e < NE; e++) {
    float w = w_all[(size_t)n * NE + e];
    if (w > 0.0f) {
      int p = atomicAdd(&cursors[e], 1);
      int s = offsets[e] + p;
      slot_token[s] = n;
      slot_w[s] = w;
      tok_slots[n * 16 + j] = s;
      j++;
    }
  }
  tok_cnt[n] = j;
}

// ---------------- gather x rows to slot-major bf16 ----------------
__global__ __launch_bounds__(256) void k_gather_x(const float* __restrict__ x,
                                                  const int* __restrict__ slot_token,
                                                  const int* __restrict__ offsets,
                                                  __bf16* __restrict__ xg) {
  int slot = blockIdx.x * 4 + (threadIdx.x >> 6);
  int lane = threadIdx.x & 63;
  int total = offsets[NE]; if (total > CAP) total = CAP;
  if (slot >= total) return;
  const float4* src = (const float4*)(x + (size_t)slot_token[slot] * NC + lane * 16);
  float4 f0 = src[0], f1 = src[1], f2 = src[2], f3 = src[3];
  bf16x8 o0, o1;
  o0[0]=f2bf(f0.x); o0[1]=f2bf(f0.y); o0[2]=f2bf(f0.z); o0[3]=f2bf(f0.w);
  o0[4]=f2bf(f1.x); o0[5]=f2bf(f1.y); o0[6]=f2bf(f1.z); o0[7]=f2bf(f1.w);
  o1[0]=f2bf(f2.x); o1[1]=f2bf(f2.y); o1[2]=f2bf(f2.z); o1[3]=f2bf(f2.w);
  o1[4]=f2bf(f3.x); o1[5]=f2bf(f3.y); o1[6]=f2bf(f3.z); o1[7]=f2bf(f3.w);
  __bf16* d = xg + (size_t)slot * NC + lane * 16;
  *(bf16x8*)d = o0;
  *(bf16x8*)(d + 8) = o1;
}

// ---------------- gather o rows to slot-major bf16 ----------------
__global__ __launch_bounds__(256) void k_gather_o(const float* __restrict__ o,
                                                  const int* __restrict__ slot_token,
                                                  const int* __restrict__ offsets,
                                                  __bf16* __restrict__ og) {
  int slot = blockIdx.x * 2 + (threadIdx.x >> 7);
  int h = threadIdx.x & 127;
  int total = offsets[NE]; if (total > CAP) total = CAP;
  if (slot >= total) return;
  og[(size_t)slot * NH + h] = f2bf(o[(size_t)slot_token[slot] * NH + h]);
}

// ---------------- shared MFMA inner tile: 64x128, BK=64 ----------------
__device__ __forceinline__ void mfma_block(const __bf16* As, const __bf16* Bs,
                                           int lane, int wrow, f32x4 acc[8]) {
#pragma unroll
  for (int ks = 0; ks < 2; ks++) {
    int koff = ks * 32 + (lane >> 4) * 8;
    bf16x8 af = *(const bf16x8*)&As[(wrow + (lane & 15)) * LDA + koff];
#pragma unroll
    for (int nt = 0; nt < 8; nt++) {
      bf16x8 bv = *(const bf16x8*)&Bs[(nt * 16 + (lane & 15)) * LDA + koff];
      acc[nt] = __builtin_amdgcn_mfma_f32_16x16x32_bf16(af, bv, acc[nt], 0, 0, 0);
    }
  }
}

// ---------------- grouped GEMM: QKV projections, slot-major in/out ----------------
__global__ __launch_bounds__(256) void k_moe_qkv2(
    const __bf16* __restrict__ xg,
    const __bf16* __restrict__ pq, const __bf16* __restrict__ pk, const __bf16* __restrict__ pv,
    const int* __restrict__ offsets, const int2* __restrict__ tile_desc,
    const int* __restrict__ n_tiles,
    __bf16* __restrict__ yq, __bf16* __restrict__ yk, __bf16* __restrict__ yv) {
  if ((int)blockIdx.y >= *n_tiles) return;
  int2 td = tile_desc[blockIdx.y];
  int e = td.x, s0 = td.y;
  int seg_end = offsets[e + 1]; if (seg_end > CAP) seg_end = CAP;
  const __bf16* Bt;
  __bf16* Yd;
  if (blockIdx.x == 0)      { Bt = pq; Yd = yq; }
  else if (blockIdx.x == 1) { Bt = pk; Yd = yk; }
  else                      { Bt = pv; Yd = yv; }
  Bt += (size_t)e * NH * NC;

  __shared__ __bf16 As[64 * LDA];
  __shared__ __bf16 Bs[128 * LDA];
  int tid = threadIdx.x, lane = tid & 63, wid = tid >> 6, wrow = wid * 16;
  f32x4 acc[8];
#pragma unroll
  for (int i = 0; i < 8; i++) { f32x4 z = {0.f, 0.f, 0.f, 0.f}; acc[i] = z; }

  for (int k0 = 0; k0 < NC; k0 += 64) {
#pragma unroll
    for (int i = 0; i < 2; i++) {   // A: contiguous bf16 slot rows
      int chunk = tid + 256 * i;
      int r = chunk >> 3, c8 = (chunk & 7) * 8;
      *(bf16x8*)&As[r * LDA + c8] = *(const bf16x8*)(xg + (size_t)(s0 + r) * NC + k0 + c8);
    }
#pragma unroll
    for (int i = 0; i < 4; i++) {   // B: P^T rows
      int chunk = tid + 256 * i;
      int r = chunk >> 3, c8 = (chunk & 7) * 8;
      *(bf16x8*)&Bs[r * LDA + c8] = *(const bf16x8*)(Bt + (size_t)r * NC + k0 + c8);
    }
    __syncthreads();
    mfma_block(As, Bs, lane, wrow, acc);
    __syncthreads();
  }
  int col = lane & 15, quad = lane >> 4;
#pragma unroll
  for (int r = 0; r < 4; r++) {
    int s = s0 + wrow + quad * 4 + r;
    if (s < seg_end) {
#pragma unroll
      for (int nt = 0; nt < 8; nt++)
        Yd[(size_t)s * NH + nt * 16 + col] = f2bf(acc[nt][r]);
    }
  }
}

// ---------------- combine Y slots -> token-major bf16 q/k/v ----------------
__global__ __launch_bounds__(256) void k_combine_qkv(
    const __bf16* __restrict__ yq, const __bf16* __restrict__ yk, const __bf16* __restrict__ yv,
    const int* __restrict__ tok_slots, const int* __restrict__ tok_cnt,
    const float* __restrict__ slot_w,
    __bf16* __restrict__ qb, __bf16* __restrict__ kb, __bf16* __restrict__ vb) {
  int token = blockIdx.x * 2 + (threadIdx.x >> 7);
  int h = threadIdx.x & 127;
  const __bf16* Y;
  __bf16* D;
  if (blockIdx.y == 0)      { Y = yq; D = qb; }
  else if (blockIdx.y == 1) { Y = yk; D = kb; }
  else                      { Y = yv; D = vb; }
  int cnt = tok_cnt[token];
  float acc = 0.f;
  for (int j = 0; j < cnt; j++) {
    int s = tok_slots[token * 16 + j];
    if (s < CAP) acc += slot_w[s] * (float)Y[(size_t)s * NH + h];
  }
  D[(size_t)token * NH + h] = f2bf(acc);
}

// ---------------- scores = q @ k^T * scale (bf16 inputs) ----------------
__global__ __launch_bounds__(256) void k_scores(const __bf16* __restrict__ q,
                                                const __bf16* __restrict__ k,
                                                float* __restrict__ scores) {
  int b = blockIdx.z;
  int t0 = blockIdx.x * 64;
  int s0 = blockIdx.y * 128;
  const __bf16* qb = q + (size_t)b * NT * NH;
  const __bf16* kb = k + (size_t)b * NT * NH;
  __shared__ __bf16 As[64 * LDA];
  __shared__ __bf16 Bs[128 * LDA];
  int tid = threadIdx.x, lane = tid & 63, wid = tid >> 6, wrow = wid * 16;
  f32x4 acc[8];
#pragma unroll
  for (int i = 0; i < 8; i++) { f32x4 z = {0.f, 0.f, 0.f, 0.f}; acc[i] = z; }

  for (int k0 = 0; k0 < NH; k0 += 64) {
#pragma unroll
    for (int i = 0; i < 2; i++) {
      int chunk = tid + 256 * i;
      int r = chunk >> 3, c8 = (chunk & 7) * 8;
      *(bf16x8*)&As[r * LDA + c8] = *(const bf16x8*)(qb + (size_t)(t0 + r) * NH + k0 + c8);
    }
#pragma unroll
    for (int i = 0; i < 4; i++) {
      int chunk = tid + 256 * i;
      int r = chunk >> 3, c8 = (chunk & 7) * 8;
      *(bf16x8*)&Bs[r * LDA + c8] = *(const bf16x8*)(kb + (size_t)(s0 + r) * NH + k0 + c8);
    }
    __syncthreads();
    mfma_block(As, Bs, lane, wrow, acc);
    __syncthreads();
  }
  const float scale = 0.08838834764831843f;  // 1/sqrt(128)
  int col = lane & 15, quad = lane >> 4;
#pragma unroll
  for (int r = 0; r < 4; r++) {
    size_t row = (size_t)b * NT + t0 + wrow + quad * 4 + r;
#pragma unroll
    for (int nt = 0; nt < 8; nt++)
      scores[row * NT + s0 + nt * 16 + col] = scale * acc[nt][r];
  }
}

// ------- row softmax, in-place: fp32 row -> bf16 probs at row start -------
__global__ __launch_bounds__(256) void k_softmax(float* __restrict__ scores) {
  int b = blockIdx.y, row = blockIdx.x;
  float* rp = scores + ((size_t)b * NT + row) * NT;
  int t = threadIdx.x;
  float4 v0 = *(const float4*)(rp + t * 8);
  float4 v1 = *(const float4*)(rp + t * 8 + 4);
  float vals[8] = {v0.x, v0.y, v0.z, v0.w, v1.x, v1.y, v1.z, v1.w};
  float m = vals[0];
#pragma unroll
  for (int i = 1; i < 8; i++) m = fmaxf(m, vals[i]);
#pragma unroll
  for (int off = 32; off; off >>= 1) m = fmaxf(m, __shfl_xor(m, off));
  __shared__ float redm[4], reds[4];
  int lane = t & 63, wid = t >> 6;
  if (lane == 0) redm[wid] = m;
  __syncthreads();
  m = fmaxf(fmaxf(redm[0], redm[1]), fmaxf(redm[2], redm[3]));
  float s = 0.f;
#pragma unroll
  for (int i = 0; i < 8; i++) { vals[i] = expf(vals[i] - m); s += vals[i]; }
#pragma unroll
  for (int off = 32; off; off >>= 1) s += __shfl_xor(s, off);
  if (lane == 0) reds[wid] = s;
  __syncthreads();
  s = reds[0] + reds[1] + reds[2] + reds[3];
  float inv = 1.f / s;
  __bf16* op = (__bf16*)rp;
  bf16x4 o0, o1;
#pragma unroll
  for (int i = 0; i < 4; i++) { o0[i] = f2bf(vals[i] * inv); o1[i] = f2bf(vals[4 + i] * inv); }
  *(bf16x4*)(op + t * 8) = o0;
  *(bf16x4*)(op + t * 8 + 4) = o1;
}

// ---------------- o = P @ v  (split-K=4, atomic accumulate) ----------------
__global__ __launch_bounds__(256) void k_av(const char* __restrict__ scores_bytes,
                                            const __bf16* __restrict__ vt,
                                            float* __restrict__ o) {
  int b = blockIdx.z;
  int t0 = blockIdx.x * 64;
  int kc = blockIdx.y;  // K chunk of 512
  __shared__ __bf16 As[64 * LDA];
  __shared__ __bf16 Bs[128 * LDA];
  int tid = threadIdx.x, lane = tid & 63, wid = tid >> 6, wrow = wid * 16;
  f32x4 acc[8];
#pragma unroll
  for (int i = 0; i < 8; i++) { f32x4 z = {0.f, 0.f, 0.f, 0.f}; acc[i] = z; }

  for (int k0 = kc * 512; k0 < kc * 512 + 512; k0 += 64) {
#pragma unroll
    for (int i = 0; i < 2; i++) {   // A: bf16 attn rows at start of fp32 row slots
      int chunk = tid + 256 * i;
      int r = chunk >> 3, c8 = (chunk & 7) * 8;
      const __bf16* src = (const __bf16*)(scores_bytes + ((size_t)b * NT + t0 + r) * NT * 4) + k0 + c8;
      *(bf16x8*)&As[r * LDA + c8] = *(const bf16x8*)src;
    }
#pragma unroll
    for (int i = 0; i < 4; i++) {   // B: v^T rows [H][T]
      int chunk = tid + 256 * i;
      int r = chunk >> 3, c8 = (chunk & 7) * 8;
      *(bf16x8*)&Bs[r * LDA + c8] = *(const bf16x8*)(vt + ((size_t)b * NH + r) * NT + k0 + c8);
    }
    __syncthreads();
    mfma_block(As, Bs, lane, wrow, acc);
    __syncthreads();
  }
  int col = lane & 15, quad = lane >> 4;
#pragma unroll
  for (int r = 0; r < 4; r++) {
    size_t row = (size_t)b * NT + t0 + wrow + quad * 4 + r;
#pragma unroll
    for (int nt = 0; nt < 8; nt++)
      atomicAdd(&o[row * NH + nt * 16 + col], acc[nt][r]);
  }
}

// ---------------- grouped GEMM: out-proj, slot-major in/out (no atomics) ----------------
__global__ __launch_bounds__(256) void k_out2(
    const __bf16* __restrict__ og, const __bf16* __restrict__ pot,
    const int* __restrict__ offsets, const int2* __restrict__ tile_desc,
    const int* __restrict__ n_tiles, __bf16* __restrict__ zy) {
  if ((int)blockIdx.y >= *n_tiles) return;
  int2 td = tile_desc[blockIdx.y];
  int e = td.x, s0 = td.y;
  int seg_end = offsets[e + 1]; if (seg_end > CAP) seg_end = CAP;
  int nc0 = blockIdx.x * 128;
  const __bf16* Bt = pot + (size_t)e * NC * NH;

  __shared__ __bf16 As[64 * LDA];
  __shared__ __bf16 Bs[128 * LDA];
  int tid = threadIdx.x, lane = tid & 63, wid = tid >> 6, wrow = wid * 16;
  f32x4 acc[8];
#pragma unroll
  for (int i = 0; i < 8; i++) { f32x4 z = {0.f, 0.f, 0.f, 0.f}; acc[i] = z; }

  for (int k0 = 0; k0 < NH; k0 += 64) {
#pragma unroll
    for (int i = 0; i < 2; i++) {   // A: contiguous bf16 slot rows of o
      int chunk = tid + 256 * i;
      int r = chunk >> 3, c8 = (chunk & 7) * 8;
      *(bf16x8*)&As[r * LDA + c8] = *(const bf16x8*)(og + (size_t)(s0 + r) * NH + k0 + c8);
    }
#pragma unroll
    for (int i = 0; i < 4; i++) {   // B: o_proj^T rows
      int chunk = tid + 256 * i;
      int r = chunk >> 3, c8 = (chunk & 7) * 8;
      *(bf16x8*)&Bs[r * LDA + c8] = *(const bf16x8*)(Bt + (size_t)(nc0 + r) * NH + k0 + c8);
    }
    __syncthreads();
    mfma_block(As, Bs, lane, wrow, acc);
    __syncthreads();
  }
  int col = lane & 15, quad = lane >> 4;
#pragma unroll
  for (int r = 0; r < 4; r++) {
    int s = s0 + wrow + quad * 4 + r;
    if (s < seg_end) {
#pragma unroll
      for (int nt = 0; nt < 8; nt++)
        zy[(size_t)s * NC + nc0 + nt * 16 + col] = f2bf(acc[nt][r]);
    }
  }
}

// ---------------- combine ZY slots -> dense fp32 out ----------------
__global__ __launch_bounds__(256) void k_combine_out(
    const __bf16* __restrict__ zy, const int* __restrict__ tok_slots,
    const int* __restrict__ tok_cnt, const float* __restrict__ slot_w,
    float* __restrict__ out) {
  int token = blockIdx.x;
  int c = threadIdx.x * 4;
  int cnt = tok_cnt[token];
  float a0 = 0.f, a1 = 0.f, a2 = 0.f, a3 = 0.f;
  for (int j = 0; j < cnt; j++) {
    int s = tok_slots[token * 16 + j];
    if (s < CAP) {
      float w = slot_w[s];
      bf16x4 z = *(const bf16x4*)&zy[(size_t)s * NC + c];
      a0 += w * (float)z[0];
      a1 += w * (float)z[1];
      a2 += w * (float)z[2];
      a3 += w * (float)z[3];
    }
  }
  float4 o = {a0, a1, a2, a3};
  *(float4*)&out[(size_t)token * NC + c] = o;
}

extern "C" void kernel_launch(void* const* d_in, const int* in_sizes, int n_in,
                              void* d_out, int out_size, void* d_ws, size_t ws_size,
                              hipStream_t stream) {
  const float* hs    = (const float*)d_in[0];  // [4,2048,1024]
  const float* sim   = (const float*)d_in[1];  // [1024,16]
  const float* gates = (const float*)d_in[2];  // [16]
  const float* qp    = (const float*)d_in[3];  // [16,1024,128]
  const float* kp    = (const float*)d_in[4];
  const float* vp    = (const float*)d_in[5];
  const float* op    = (const float*)d_in[6];  // [16,128,1024]
  float* out = (float*)d_out;
  char* ws = (char*)d_ws;

  // ---- workspace arena (~96 MiB peak, aliased) ----
  const size_t M = 1048576;
  __bf16* PQT = (__bf16*)(ws + 0 * M);         // 4 MiB each
  __bf16* PKT = (__bf16*)(ws + 4 * M);
  __bf16* PVT = (__bf16*)(ws + 8 * M);
  __bf16* POT = (__bf16*)(ws + 12 * M);
  __bf16* Qb  = (__bf16*)(ws + 16 * M);        // 2 MiB each, token-major bf16
  __bf16* Kb  = (__bf16*)(ws + 18 * M);
  __bf16* Vb  = (__bf16*)(ws + 20 * M);
  __bf16* VT  = (__bf16*)(ws + 22 * M);        // 2 MiB
  float*  O   = (float*)(ws + 24 * M);         // 4 MiB fp32
  float*  WALL = (float*)(ws + 28 * M);        // 512 KiB
  int*    STOK = (int*)(ws + 28 * M + 524288); // 512 KiB (full 131072 slots)
  float*  SW   = (float*)(ws + 28 * M + 1048576);
  int*    TSL  = (int*)(ws + 28 * M + 1572864);  // tok_slots 512 KiB
  int*    TCN  = (int*)(ws + 28 * M + 2097152);  // tok_cnt 32 KiB
  double* SNORM = (double*)(ws + 28 * M + 2129920);
  double* SIG   = SNORM + 16;
  int* CNT = (int*)(ws + 28 * M + 2130432);
  int* OFF = CNT + 16;
  int* CUR = CNT + 40;
  int* NTL = CNT + 60;
  int2* DESC = (int2*)(ws + 28 * M + 2131456);
  // R region (32M..96M), aliased by lifetime:
  __bf16* XG = (__bf16*)(ws + 32 * M);         // XGROWS*2048 B = 36.1 MiB (dies before SC)
  __bf16* YQ = (__bf16*)(ws + 72 * M);         // 4.5 MiB each (die before SC)
  __bf16* YK = (__bf16*)(ws + 77 * M);
  __bf16* YV = (__bf16*)(ws + 82 * M);
  float*  SC = (float*)(ws + 32 * M);          // 64 MiB (dies after k_av)
  __bf16* OG = (__bf16*)(ws + 32 * M);         // 4.5 MiB (after SC dead)
  __bf16* ZY = (__bf16*)(ws + 40 * M);         // 36.1 MiB (after SC dead)

  hipMemsetAsync(CNT, 0, 512, stream);
  hipMemsetAsync(O, 0, 4 * M, stream);

  k_prep<<<1, 256, 0, stream>>>(sim, gates, SNORM, SIG);
  k_transpose<<<dim3(32, 4, 16), 256, 0, stream>>>(qp, PQT, 1024, 128);
  k_transpose<<<dim3(32, 4, 16), 256, 0, stream>>>(kp, PKT, 1024, 128);
  k_transpose<<<dim3(32, 4, 16), 256, 0, stream>>>(vp, PVT, 1024, 128);
  k_transpose<<<dim3(4, 32, 16), 256, 0, stream>>>(op, POT, 128, 1024);
  k_gating2<<<NTOK / 16, 256, 0, stream>>>(hs, sim, SNORM, SIG, WALL, CNT);
  k_scan<<<1, 64, 0, stream>>>(CNT, OFF, DESC, NTL);
  k_assign<<<NTOK / 256, 256, 0, stream>>>(WALL, OFF, CUR, STOK, SW, TSL, TCN);
  k_gather_x<<<CAP / 4, 256, 0, stream>>>(hs, STOK, OFF, XG);
  k_moe_qkv2<<<dim3(3, NTILE_MAX), 256, 0, stream>>>(XG, PQT, PKT, PVT, OFF, DESC, NTL, YQ, YK, YV);
  k_combine_qkv<<<dim3(NTOK / 2, 3), 256, 0, stream>>>(YQ, YK, YV, TSL, TCN, SW, Qb, Kb, Vb);
  k_scores<<<dim3(32, 16, 4), 256, 0, stream>>>(Qb, Kb, SC);
  k_softmax<<<dim3(2048, 4), 256, 0, stream>>>(SC);
  k_transpose_bf<<<dim3(64, 4, 4), 256, 0, stream>>>(Vb, VT, 2048, 128);
  k_av<<<dim3(32, 4, 4), 256, 0, stream>>>((const char*)SC, VT, O);
  k_gather_o<<<CAP / 2, 256, 0, stream>>>(O, STOK, OFF, OG);
  k_out2<<<dim3(8, NTILE_MAX), 256, 0, stream>>>(OG, POT, OFF, DESC, NTL, ZY);
  k_combine_out<<<NTOK, 256, 0, stream>>>(ZY, TSL, TCN, SW, out);
}